// Round 1
// baseline (204.435 us; speedup 1.0000x reference)
//
#include <hip/hip_runtime.h>
#include <hip/hip_cooperative_groups.h>

namespace cg = cooperative_groups;

// O[b,q,e] = sum_k (Q·K)/ (sqrt(128)*qk_sf) * V  ==  Q @ (K^T V) * s   (no softmax)
// B=8, S=2048, D=128 fp32.
// Fused single cooperative kernel, 3 phases:
//  P1: P'[blk][e=128][d=64] = partial V^T K (bf16)      (512 "blk" units)
//  P2: Tt[b][e][d] = s * sum_chunks P'   (bf16)
//  P3: O = Q @ T via mfma_f32_16x16x32_bf16
// grid.sync() between phases; bodies identical to the verified 3-kernel pipeline.

#define BATCH 8
#define SEQ 2048
#define DIM 128

typedef __attribute__((ext_vector_type(8))) short short8;
typedef __attribute__((ext_vector_type(4))) float f32x4;

__device__ __forceinline__ unsigned int f2bf(float f) {
    unsigned int u = __float_as_uint(f);
    u += 0x7fffu + ((u >> 16) & 1u);   // RNE
    return u >> 16;
}

// ---------------- fused cooperative kernel ---------------------------------
__global__ __launch_bounds__(256, 2) void fused_qktv(
    const float* __restrict__ Q, const float* __restrict__ K,
    const float* __restrict__ V, const float* __restrict__ qk_sf,
    unsigned short* __restrict__ P, unsigned short* __restrict__ Tt,
    float* __restrict__ O)
{
    // union of phase-1 (48 KB) and phase-3 (42.5 KB) shared usage
    __shared__ __align__(16) unsigned char smem[64 * 128 * 4 + 64 * 64 * 4];
    const int tid = threadIdx.x;
    cg::grid_group grid = cg::this_grid();

    // ======== Phase 1: partial V^T K  (blk = ((b*32+kc)*2+dh)) =============
    {
        float* Vc = (float*)smem;                    // 64*128 f32 = 32 KB
        float* Kc = (float*)(smem + 64 * 128 * 4);   // 64*64  f32 = 16 KB
        const int blk = blockIdx.x;
        const int b   = blk >> 6;
        const int kc  = (blk >> 1) & 31;
        const int dh  = blk & 1;

        const float* Vg = V + ((size_t)b * SEQ + kc * 64) * DIM;
        const float* Kg = K + ((size_t)b * SEQ + kc * 64) * DIM + dh * 64;

        #pragma unroll
        for (int i = 0; i < 8; i++) {                 // 2048 float4
            int idx = tid + i * 256;
            ((float4*)Vc)[idx] = ((const float4*)Vg)[idx];
        }
        #pragma unroll
        for (int i = 0; i < 4; i++) {                 // 1024 float4 (64-col slice)
            int idx = tid + i * 256;
            int r = idx >> 4, c = idx & 15;
            ((float4*)Kc)[idx] = *(const float4*)(Kg + r * DIM + c * 4);
        }
        __syncthreads();

        const int td = tid & 15;    // d-group: 4 consecutive d
        const int te = tid >> 4;    // e-group: 8 consecutive e

        float acc[8][4];
        #pragma unroll
        for (int i = 0; i < 8; i++)
            #pragma unroll
            for (int j = 0; j < 4; j++) acc[i][j] = 0.0f;

        for (int k = 0; k < 64; k++) {
            const float4 kd = *(const float4*)&Kc[k * 64 + td * 4];
            const float4 va = *(const float4*)&Vc[k * 128 + te * 8];
            const float4 vb = *(const float4*)&Vc[k * 128 + te * 8 + 4];
            const float ve[8] = {va.x, va.y, va.z, va.w, vb.x, vb.y, vb.z, vb.w};
            const float kv[4] = {kd.x, kd.y, kd.z, kd.w};
            #pragma unroll
            for (int i = 0; i < 8; i++)
                #pragma unroll
                for (int j = 0; j < 4; j++)
                    acc[i][j] = fmaf(ve[i], kv[j], acc[i][j]);
        }

        unsigned short* Pb = P + (size_t)blk * 8192;
        #pragma unroll
        for (int i = 0; i < 8; i++) {
            uint2 w;
            w.x = f2bf(acc[i][0]) | (f2bf(acc[i][1]) << 16);
            w.y = f2bf(acc[i][2]) | (f2bf(acc[i][3]) << 16);
            *(uint2*)(Pb + (te * 8 + i) * 64 + td * 4) = w;
        }
    }

    grid.sync();

    // ======== Phase 2: reduce partials -> Tt[b][e][d] * s ==================
    // 131072 threads == 8*128*128 outputs: one scalar output per thread,
    // coalesced 2B loads/stores, spread over the whole chip.
    {
        const int gid = blockIdx.x * 256 + tid;
        const int b   = gid >> 14;
        const int e   = (gid >> 7) & 127;
        const int d   = gid & 127;
        const int dh  = d >> 6;
        const int dl  = d & 63;

        const unsigned short* Pp = P + (size_t)(b * 64 + dh) * 8192 + e * 64 + dl;
        float a = 0.0f;
        #pragma unroll 8
        for (int kc = 0; kc < 32; kc++)
            a += __uint_as_float((unsigned int)Pp[(size_t)kc * 16384] << 16);

        const float s = 1.0f / (sqrtf(128.0f) * qk_sf[0]);
        Tt[(size_t)b * 16384 + e * 128 + d] = (unsigned short)f2bf(a * s);
    }

    grid.sync();

    // ======== Phase 3: O = Q @ T  (MFMA bf16), blk = b*64 + qc =============
    {
        unsigned short* Ts = (unsigned short*)smem;            // 128*136*2 = 34816 B
        unsigned short* Qs = (unsigned short*)(smem + 34816);  // 32*136*2  =  8704 B
        const int b   = blockIdx.x >> 6;
        const int q0  = (blockIdx.x & 63) * 32;

        const uint4* Tg = (const uint4*)(Tt + (size_t)b * 16384);  // 2048 uint4
        #pragma unroll
        for (int i = 0; i < 8; i++) {
            int idx = tid + i * 256;
            int row = idx >> 4, c = idx & 15;
            *(uint4*)&Ts[row * 136 + c * 8] = Tg[idx];
        }
        const float4* Qg = (const float4*)(Q + ((size_t)b * SEQ + q0) * DIM); // 1024 float4
        #pragma unroll
        for (int i = 0; i < 4; i++) {
            int idx = tid + i * 256;
            int row = idx >> 5, c = idx & 31;
            float4 v = Qg[idx];
            uint2 w;
            w.x = f2bf(v.x) | (f2bf(v.y) << 16);
            w.y = f2bf(v.z) | (f2bf(v.w) << 16);
            *(uint2*)&Qs[row * 136 + c * 4] = w;
        }
        __syncthreads();

        const int wave = tid >> 6, lane = tid & 63;
        const int lm   = lane & 15, quad = lane >> 4;
        const int mrow = (wave & 1) * 16;        // q-tile within block
        const int n0   = (wave >> 1) * 64;       // e-range (4 n-tiles of 16)

        f32x4 acc[4] = {{0,0,0,0},{0,0,0,0},{0,0,0,0},{0,0,0,0}};
        #pragma unroll
        for (int ks = 0; ks < 4; ks++) {         // K = 128 in steps of 32
            short8 a = *(const short8*)&Qs[(mrow + lm) * 136 + ks * 32 + quad * 8];
            #pragma unroll
            for (int nt = 0; nt < 4; nt++) {
                short8 bb = *(const short8*)&Ts[(n0 + nt * 16 + lm) * 136 + ks * 32 + quad * 8];
                acc[nt] = __builtin_amdgcn_mfma_f32_16x16x32_bf16(a, bb, acc[nt], 0, 0, 0);
            }
        }

        float* Og = O + ((size_t)b * SEQ + q0) * DIM;
        #pragma unroll
        for (int nt = 0; nt < 4; nt++)
            #pragma unroll
            for (int r = 0; r < 4; r++) {
                const int row = mrow + quad * 4 + r;        // C/D: row = quad*4 + reg
                const int col = n0 + nt * 16 + lm;          //      col = lane&15
                Og[row * DIM + col] = acc[nt][r];
            }
    }
}

// ---------------- fallback: original verified 3-kernel pipeline -------------
__global__ __launch_bounds__(256) void vtk_partial(const float* __restrict__ K,
                                                   const float* __restrict__ V,
                                                   unsigned short* __restrict__ P) {
    __shared__ float Vc[64 * 128];
    __shared__ float Kc[64 * 64];
    const int blk = blockIdx.x;
    const int b   = blk >> 6;
    const int kc  = (blk >> 1) & 31;
    const int dh  = blk & 1;
    const int tid = threadIdx.x;

    const float* Vg = V + ((size_t)b * SEQ + kc * 64) * DIM;
    const float* Kg = K + ((size_t)b * SEQ + kc * 64) * DIM + dh * 64;

    #pragma unroll
    for (int i = 0; i < 8; i++) {
        int idx = tid + i * 256;
        ((float4*)Vc)[idx] = ((const float4*)Vg)[idx];
    }
    #pragma unroll
    for (int i = 0; i < 4; i++) {
        int idx = tid + i * 256;
        int r = idx >> 4, c = idx & 15;
        ((float4*)Kc)[idx] = *(const float4*)(Kg + r * DIM + c * 4);
    }
    __syncthreads();

    const int td = tid & 15;
    const int te = tid >> 4;

    float acc[8][4];
    #pragma unroll
    for (int i = 0; i < 8; i++)
        #pragma unroll
        for (int j = 0; j < 4; j++) acc[i][j] = 0.0f;

    for (int k = 0; k < 64; k++) {
        const float4 kd = *(const float4*)&Kc[k * 64 + td * 4];
        const float4 va = *(const float4*)&Vc[k * 128 + te * 8];
        const float4 vb = *(const float4*)&Vc[k * 128 + te * 8 + 4];
        const float ve[8] = {va.x, va.y, va.z, va.w, vb.x, vb.y, vb.z, vb.w};
        const float kv[4] = {kd.x, kd.y, kd.z, kd.w};
        #pragma unroll
        for (int i = 0; i < 8; i++)
            #pragma unroll
            for (int j = 0; j < 4; j++)
                acc[i][j] = fmaf(ve[i], kv[j], acc[i][j]);
    }

    unsigned short* Pb = P + (size_t)blk * 8192;
    #pragma unroll
    for (int i = 0; i < 8; i++) {
        uint2 w;
        w.x = f2bf(acc[i][0]) | (f2bf(acc[i][1]) << 16);
        w.y = f2bf(acc[i][2]) | (f2bf(acc[i][3]) << 16);
        *(uint2*)(Pb + (te * 8 + i) * 64 + td * 4) = w;
    }
}

__global__ __launch_bounds__(256) void reduce_t(const unsigned short* __restrict__ P,
                                                const float* __restrict__ qk_sf,
                                                unsigned short* __restrict__ Tt) {
    const int u   = blockIdx.x * 256 + threadIdx.x;
    const int b   = u >> 12;
    const int rem = u & 4095;
    const int e   = rem >> 5;
    const int d0  = (rem & 31) * 4;
    const int dh  = d0 >> 6;
    const int dl  = d0 & 63;

    const unsigned short* Pb = P + ((size_t)(b * 64 + dh) * 8192) + e * 64 + dl;
    float a0 = 0.f, a1 = 0.f, a2 = 0.f, a3 = 0.f;
    #pragma unroll 8
    for (int kc = 0; kc < 32; kc++) {
        uint2 w = *(const uint2*)(Pb + (size_t)kc * 16384);
        a0 += __uint_as_float(w.x << 16);
        a1 += __uint_as_float(w.x & 0xffff0000u);
        a2 += __uint_as_float(w.y << 16);
        a3 += __uint_as_float(w.y & 0xffff0000u);
    }
    const float s = 1.0f / (sqrtf(128.0f) * qk_sf[0]);
    uint2 o;
    o.x = f2bf(a0 * s) | (f2bf(a1 * s) << 16);
    o.y = f2bf(a2 * s) | (f2bf(a3 * s) << 16);
    *(uint2*)(Tt + (size_t)b * 16384 + e * 128 + d0) = o;
}

__global__ __launch_bounds__(256) void qt_mfma(const float* __restrict__ Q,
                                               const unsigned short* __restrict__ Tt,
                                               float* __restrict__ O) {
    __shared__ unsigned short Ts[128 * 136];
    __shared__ unsigned short Qs[32 * 136];
    const int b   = blockIdx.x >> 6;
    const int q0  = (blockIdx.x & 63) * 32;
    const int tid = threadIdx.x;

    const uint4* Tg = (const uint4*)(Tt + (size_t)b * 16384);
    #pragma unroll
    for (int i = 0; i < 8; i++) {
        int idx = tid + i * 256;
        int row = idx >> 4, c = idx & 15;
        *(uint4*)&Ts[row * 136 + c * 8] = Tg[idx];
    }
    const float4* Qg = (const float4*)(Q + ((size_t)b * SEQ + q0) * DIM);
    #pragma unroll
    for (int i = 0; i < 4; i++) {
        int idx = tid + i * 256;
        int row = idx >> 5, c = idx & 31;
        float4 v = Qg[idx];
        uint2 w;
        w.x = f2bf(v.x) | (f2bf(v.y) << 16);
        w.y = f2bf(v.z) | (f2bf(v.w) << 16);
        *(uint2*)&Qs[row * 136 + c * 4] = w;
    }
    __syncthreads();

    const int wave = tid >> 6, lane = tid & 63;
    const int lm   = lane & 15, quad = lane >> 4;
    const int mrow = (wave & 1) * 16;
    const int n0   = (wave >> 1) * 64;

    f32x4 acc[4] = {{0,0,0,0},{0,0,0,0},{0,0,0,0},{0,0,0,0}};
    #pragma unroll
    for (int ks = 0; ks < 4; ks++) {
        short8 a = *(const short8*)&Qs[(mrow + lm) * 136 + ks * 32 + quad * 8];
        #pragma unroll
        for (int nt = 0; nt < 4; nt++) {
            short8 bb = *(const short8*)&Ts[(n0 + nt * 16 + lm) * 136 + ks * 32 + quad * 8];
            acc[nt] = __builtin_amdgcn_mfma_f32_16x16x32_bf16(a, bb, acc[nt], 0, 0, 0);
        }
    }

    float* Og = O + ((size_t)b * SEQ + q0) * DIM;
    #pragma unroll
    for (int nt = 0; nt < 4; nt++)
        #pragma unroll
        for (int r = 0; r < 4; r++) {
            const int row = mrow + quad * 4 + r;
            const int col = n0 + nt * 16 + lm;
            Og[row * DIM + col] = acc[nt][r];
        }
}

extern "C" void kernel_launch(void* const* d_in, const int* in_sizes, int n_in,
                              void* d_out, int out_size, void* d_ws, size_t ws_size,
                              hipStream_t stream) {
    const float* qk_sf = (const float*)d_in[1];
    const float* Q = (const float*)d_in[2];
    const float* K = (const float*)d_in[3];
    const float* V = (const float*)d_in[4];
    float* O = (float*)d_out;

    unsigned short* P  = (unsigned short*)d_ws;                       // 512*8192*2B = 8 MB
    unsigned short* Tt = (unsigned short*)((char*)d_ws + (size_t)512 * 8192 * 2);

    void* args[] = {(void*)&Q, (void*)&K, (void*)&V, (void*)&qk_sf,
                    (void*)&P, (void*)&Tt, (void*)&O};
    hipError_t err = hipLaunchCooperativeKernel((const void*)fused_qktv,
                                                dim3(512), dim3(256),
                                                args, 0, stream);
    if (err != hipSuccess) {
        // fallback: verified 3-kernel pipeline
        vtk_partial<<<dim3(512), dim3(256), 0, stream>>>(K, V, P);
        reduce_t<<<dim3(128), dim3(256), 0, stream>>>(P, qk_sf, Tt);
        qt_mfma<<<dim3(BATCH * 64), dim3(256), 0, stream>>>(Q, Tt, O);
    }
}

// Round 2
// 104.885 us; speedup vs baseline: 1.9491x; 1.9491x over previous
//
#include <hip/hip_runtime.h>

// O[b,q,e] = sum_k (Q·K)/(sqrt(128)*qk_sf) * V  ==  (Q*s) @ (K^T V)   (no softmax)
// B=8, S=2048, D=128 fp32.
// 2-kernel pipeline, graph-capturable, no grid.sync:
//  memset: T[b][e][d] fp32 = 0                         (512 KB workspace)
//  K1: vtk_atomic — per (b,kc,dh) chunk computes partial V^T K in registers,
//      stages to LDS in [e][d] order, then coalesced fp32 atomicAdd into T.
//  K2: qt_f32t  — O = (Q*s) @ T via mfma_f32_16x16x32_bf16; T converted
//      fp32->bf16 on load (T reads are L2-resident: 64 blocks share each b).

#define BATCH 8
#define SEQ 2048
#define DIM 128

typedef __attribute__((ext_vector_type(8))) short short8;
typedef __attribute__((ext_vector_type(4))) float f32x4;

__device__ __forceinline__ unsigned int f2bf(float f) {
    unsigned int u = __float_as_uint(f);
    u += 0x7fffu + ((u >> 16) & 1u);   // RNE
    return u >> 16;
}

// ---------------- K1: partial V^T K -> atomicAdd fp32 into T ---------------
// grid = 512: blockIdx = ((b*32 + kc)*2 + dh); 64 k-rows, d-half of 64
__global__ __launch_bounds__(256) void vtk_atomic(const float* __restrict__ K,
                                                  const float* __restrict__ V,
                                                  float* __restrict__ T) {
    __shared__ float Vc[64 * 128];   // 32 KB (reused as epilogue staging)
    __shared__ float Kc[64 * 64];    // 16 KB
    const int blk = blockIdx.x;
    const int b   = blk >> 6;
    const int kc  = (blk >> 1) & 31;
    const int dh  = blk & 1;
    const int tid = threadIdx.x;

    const float* Vg = V + ((size_t)b * SEQ + kc * 64) * DIM;
    const float* Kg = K + ((size_t)b * SEQ + kc * 64) * DIM + dh * 64;

    #pragma unroll
    for (int i = 0; i < 8; i++) {                 // 2048 float4
        int idx = tid + i * 256;
        ((float4*)Vc)[idx] = ((const float4*)Vg)[idx];
    }
    #pragma unroll
    for (int i = 0; i < 4; i++) {                 // 1024 float4 (64-col slice)
        int idx = tid + i * 256;
        int r = idx >> 4, c = idx & 15;
        ((float4*)Kc)[idx] = *(const float4*)(Kg + r * DIM + c * 4);
    }
    __syncthreads();

    const int td = tid & 15;    // d-group: 4 consecutive d
    const int te = tid >> 4;    // e-group: 8 consecutive e

    float acc[8][4];
    #pragma unroll
    for (int i = 0; i < 8; i++)
        #pragma unroll
        for (int j = 0; j < 4; j++) acc[i][j] = 0.0f;

    for (int k = 0; k < 64; k++) {
        const float4 kd = *(const float4*)&Kc[k * 64 + td * 4];
        const float4 va = *(const float4*)&Vc[k * 128 + te * 8];
        const float4 vb = *(const float4*)&Vc[k * 128 + te * 8 + 4];
        const float ve[8] = {va.x, va.y, va.z, va.w, vb.x, vb.y, vb.z, vb.w};
        const float kv[4] = {kd.x, kd.y, kd.z, kd.w};
        #pragma unroll
        for (int i = 0; i < 8; i++)
            #pragma unroll
            for (int j = 0; j < 4; j++)
                acc[i][j] = fmaf(ve[i], kv[j], acc[i][j]);
    }

    __syncthreads();   // everyone done reading Vc/Kc; reclaim Vc for staging

    // stage acc -> Vc as [e(0..127)][dl(0..63)] so atomics can be linearized
    #pragma unroll
    for (int i = 0; i < 8; i++) {
        float4 w = {acc[i][0], acc[i][1], acc[i][2], acc[i][3]};
        *(float4*)&Vc[(te * 8 + i) * 64 + td * 4] = w;
    }
    __syncthreads();

    // coalesced atomics: consecutive lanes -> consecutive d (256 B / wave-instr)
    float* Tb = T + (size_t)b * (DIM * DIM) + dh * 64;
    #pragma unroll
    for (int i = 0; i < 32; i++) {
        int u  = i * 256 + tid;     // 0..8191
        int e  = u >> 6;
        int dl = u & 63;
        atomicAdd(&Tb[e * DIM + dl], Vc[u]);
    }
}

// ---------------- K2: O = (Q*s) @ T  (MFMA bf16) ---------------------------
// grid = 512: blockIdx = b*64 + qc (32 q-rows per block)
__global__ __launch_bounds__(256) void qt_f32t(const float* __restrict__ Q,
                                               const float* __restrict__ T,
                                               const float* __restrict__ qk_sf,
                                               float* __restrict__ O) {
    __shared__ unsigned short Ts[128 * 136];  // T[e][d] bf16, pad 136
    __shared__ unsigned short Qs[32 * 136];   // Q[q][d] bf16 (pre-scaled)
    const int b   = blockIdx.x >> 6;
    const int q0  = (blockIdx.x & 63) * 32;
    const int tid = threadIdx.x;

    const float s = 1.0f / (sqrtf(128.0f) * qk_sf[0]);

    // load T fp32 (L2-resident after first block of this b), convert to bf16
    const float4* Tg = (const float4*)(T + (size_t)b * (DIM * DIM)); // 4096 float4
    #pragma unroll
    for (int i = 0; i < 16; i++) {
        int idx = tid + i * 256;
        int row = idx >> 5, c = idx & 31;   // row=e, c=float4 within d
        float4 v = Tg[idx];
        uint2 w;
        w.x = f2bf(v.x) | (f2bf(v.y) << 16);
        w.y = f2bf(v.z) | (f2bf(v.w) << 16);
        *(uint2*)&Ts[row * 136 + c * 4] = w;
    }
    const float4* Qg = (const float4*)(Q + ((size_t)b * SEQ + q0) * DIM); // 1024 float4
    #pragma unroll
    for (int i = 0; i < 4; i++) {
        int idx = tid + i * 256;
        int row = idx >> 5, c = idx & 31;
        float4 v = Qg[idx];
        uint2 w;
        w.x = f2bf(v.x * s) | (f2bf(v.y * s) << 16);
        w.y = f2bf(v.z * s) | (f2bf(v.w * s) << 16);
        *(uint2*)&Qs[row * 136 + c * 4] = w;
    }
    __syncthreads();

    const int wave = tid >> 6, lane = tid & 63;
    const int lm   = lane & 15, quad = lane >> 4;
    const int mrow = (wave & 1) * 16;        // q-tile within block
    const int n0   = (wave >> 1) * 64;       // e-range (4 n-tiles of 16)

    f32x4 acc[4] = {{0,0,0,0},{0,0,0,0},{0,0,0,0},{0,0,0,0}};
    #pragma unroll
    for (int ks = 0; ks < 4; ks++) {         // K = 128 in steps of 32
        short8 a = *(const short8*)&Qs[(mrow + lm) * 136 + ks * 32 + quad * 8];
        #pragma unroll
        for (int nt = 0; nt < 4; nt++) {
            short8 bb = *(const short8*)&Ts[(n0 + nt * 16 + lm) * 136 + ks * 32 + quad * 8];
            acc[nt] = __builtin_amdgcn_mfma_f32_16x16x32_bf16(a, bb, acc[nt], 0, 0, 0);
        }
    }

    float* Og = O + ((size_t)b * SEQ + q0) * DIM;
    #pragma unroll
    for (int nt = 0; nt < 4; nt++)
        #pragma unroll
        for (int r = 0; r < 4; r++) {
            const int row = mrow + quad * 4 + r;        // C/D: row = quad*4 + reg
            const int col = n0 + nt * 16 + lm;          //      col = lane&15
            Og[row * DIM + col] = acc[nt][r];
        }
}

extern "C" void kernel_launch(void* const* d_in, const int* in_sizes, int n_in,
                              void* d_out, int out_size, void* d_ws, size_t ws_size,
                              hipStream_t stream) {
    const float* qk_sf = (const float*)d_in[1];
    const float* Q = (const float*)d_in[2];
    const float* K = (const float*)d_in[3];
    const float* V = (const float*)d_in[4];
    float* O = (float*)d_out;

    float* T = (float*)d_ws;   // 8*128*128*4 B = 512 KB fp32 accumulator

    hipMemsetAsync(T, 0, (size_t)BATCH * DIM * DIM * sizeof(float), stream);
    vtk_atomic<<<dim3(512), dim3(256), 0, stream>>>(K, V, T);
    qt_f32t<<<dim3(BATCH * 64), dim3(256), 0, stream>>>(Q, T, qk_sf, O);
}

// Round 4
// 94.485 us; speedup vs baseline: 2.1637x; 1.1101x over previous
//
#include <hip/hip_runtime.h>

// O[b,q,e] = sum_k (Q·K)/ (sqrt(128)*qk_sf) * V  ==  Q @ (K^T V) * s   (no softmax)
// B=8, S=2048, D=128 fp32.
// Verified 3-kernel P-staging pipeline (96.5 us baseline structure):
// K1: P'[blk][e=128][d=64] = partial V^T K (bf16, transposed for K2/K3)
//     - acc as f32x4 vector ops so clang can emit packed fp32 FMA
// K2: Tt[b][e][d] = s * sum_chunks P'   (bf16, scale folded)
// K3: O = Q @ T via mfma_f32_16x16x32_bf16, B-frag reads Tt contiguously.
// NO atomics, NO cooperative launch (both measured slower in R1/R2).

#define BATCH 8
#define SEQ 2048
#define DIM 128

typedef __attribute__((ext_vector_type(8))) short short8;
typedef __attribute__((ext_vector_type(4))) float f32x4;

__device__ __forceinline__ unsigned int f2bf(float f) {
    unsigned int u = __float_as_uint(f);
    u += 0x7fffu + ((u >> 16) & 1u);   // RNE
    return u >> 16;
}

// ---------------- K1: partial V^T K ----------------------------------------
// grid = 512: blockIdx = ((b*32 + kc)*2 + dh); 64 k-rows, d-half of 64
__global__ __launch_bounds__(256) void vtk_partial(const float* __restrict__ K,
                                                   const float* __restrict__ V,
                                                   unsigned short* __restrict__ P) {
    __shared__ float Vc[64 * 128];   // 32 KB
    __shared__ float Kc[64 * 64];    // 16 KB
    const int blk = blockIdx.x;
    const int b   = blk >> 6;
    const int kc  = (blk >> 1) & 31;
    const int dh  = blk & 1;
    const int tid = threadIdx.x;

    const float* Vg = V + ((size_t)b * SEQ + kc * 64) * DIM;
    const float* Kg = K + ((size_t)b * SEQ + kc * 64) * DIM + dh * 64;

    #pragma unroll
    for (int i = 0; i < 8; i++) {                 // 2048 float4
        int idx = tid + i * 256;
        ((float4*)Vc)[idx] = ((const float4*)Vg)[idx];
    }
    #pragma unroll
    for (int i = 0; i < 4; i++) {                 // 1024 float4 (64-col slice)
        int idx = tid + i * 256;
        int r = idx >> 4, c = idx & 15;
        ((float4*)Kc)[idx] = *(const float4*)(Kg + r * DIM + c * 4);
    }
    __syncthreads();

    const int td = tid & 15;    // d-group: 4 consecutive d
    const int te = tid >> 4;    // e-group: 8 consecutive e

    f32x4 acc[8];
    #pragma unroll
    for (int i = 0; i < 8; i++) acc[i] = (f32x4){0.f, 0.f, 0.f, 0.f};

    for (int k = 0; k < 64; k++) {
        const f32x4 kd = *(const f32x4*)&Kc[k * 64 + td * 4];
        const float4 va = *(const float4*)&Vc[k * 128 + te * 8];
        const float4 vb = *(const float4*)&Vc[k * 128 + te * 8 + 4];
        const float ve[8] = {va.x, va.y, va.z, va.w, vb.x, vb.y, vb.z, vb.w};
        #pragma unroll
        for (int i = 0; i < 8; i++)
            acc[i] += kd * ve[i];                 // packed f32 FMA candidate
    }

    unsigned short* Pb = P + (size_t)blk * 8192;
    #pragma unroll
    for (int i = 0; i < 8; i++) {
        uint2 w;
        w.x = f2bf(acc[i][0]) | (f2bf(acc[i][1]) << 16);
        w.y = f2bf(acc[i][2]) | (f2bf(acc[i][3]) << 16);
        *(uint2*)(Pb + (te * 8 + i) * 64 + td * 4) = w;
    }
}

// ---------------- K2: reduce partials -> Tt[b][e][d] * s --------------------
// grid = 128 x 256 : one thread = 4 consecutive d for one (b,e)
__global__ __launch_bounds__(256) void reduce_t(const unsigned short* __restrict__ P,
                                                const float* __restrict__ qk_sf,
                                                unsigned short* __restrict__ Tt) {
    const int u   = blockIdx.x * 256 + threadIdx.x;  // 0..32767
    const int b   = u >> 12;
    const int rem = u & 4095;
    const int e   = rem >> 5;
    const int d0  = (rem & 31) * 4;
    const int dh  = d0 >> 6;
    const int dl  = d0 & 63;

    const unsigned short* Pb = P + ((size_t)(b * 64 + dh) * 8192) + e * 64 + dl;
    float a0 = 0.f, a1 = 0.f, a2 = 0.f, a3 = 0.f;
    #pragma unroll 8
    for (int kc = 0; kc < 32; kc++) {
        uint2 w = *(const uint2*)(Pb + (size_t)kc * 16384);
        a0 += __uint_as_float(w.x << 16);
        a1 += __uint_as_float(w.x & 0xffff0000u);
        a2 += __uint_as_float(w.y << 16);
        a3 += __uint_as_float(w.y & 0xffff0000u);
    }
    const float s = 1.0f / (sqrtf(128.0f) * qk_sf[0]);
    uint2 o;
    o.x = f2bf(a0 * s) | (f2bf(a1 * s) << 16);
    o.y = f2bf(a2 * s) | (f2bf(a3 * s) << 16);
    *(uint2*)(Tt + (size_t)b * 16384 + e * 128 + d0) = o;
}

// ---------------- K3: O = Q @ T  (MFMA bf16) --------------------------------
// grid = 512: blockIdx = b*64 + qc (32 q-rows per block)
__global__ __launch_bounds__(256) void qt_mfma(const float* __restrict__ Q,
                                               const unsigned short* __restrict__ Tt,
                                               float* __restrict__ O) {
    __shared__ unsigned short Ts[128 * 136];  // Tt[e][d], pad 136 (272 B row, 16B-aligned)
    __shared__ unsigned short Qs[32 * 136];   // Q[q][d] bf16
    const int b   = blockIdx.x >> 6;
    const int q0  = (blockIdx.x & 63) * 32;
    const int tid = threadIdx.x;

    const uint4* Tg = (const uint4*)(Tt + (size_t)b * 16384);  // 2048 uint4
    #pragma unroll
    for (int i = 0; i < 8; i++) {
        int idx = tid + i * 256;
        int row = idx >> 4, c = idx & 15;
        *(uint4*)&Ts[row * 136 + c * 8] = Tg[idx];
    }
    const float4* Qg = (const float4*)(Q + ((size_t)b * SEQ + q0) * DIM); // 1024 float4
    #pragma unroll
    for (int i = 0; i < 4; i++) {
        int idx = tid + i * 256;
        int row = idx >> 5, c = idx & 31;
        float4 v = Qg[idx];
        uint2 w;
        w.x = f2bf(v.x) | (f2bf(v.y) << 16);
        w.y = f2bf(v.z) | (f2bf(v.w) << 16);
        *(uint2*)&Qs[row * 136 + c * 4] = w;
    }
    __syncthreads();

    const int wave = tid >> 6, lane = tid & 63;
    const int lm   = lane & 15, quad = lane >> 4;
    const int mrow = (wave & 1) * 16;        // q-tile within block
    const int n0   = (wave >> 1) * 64;       // e-range (4 n-tiles of 16)

    f32x4 acc[4] = {{0,0,0,0},{0,0,0,0},{0,0,0,0},{0,0,0,0}};
    #pragma unroll
    for (int ks = 0; ks < 4; ks++) {         // K = 128 in steps of 32
        short8 a = *(const short8*)&Qs[(mrow + lm) * 136 + ks * 32 + quad * 8];
        #pragma unroll
        for (int nt = 0; nt < 4; nt++) {
            short8 bb = *(const short8*)&Ts[(n0 + nt * 16 + lm) * 136 + ks * 32 + quad * 8];
            acc[nt] = __builtin_amdgcn_mfma_f32_16x16x32_bf16(a, bb, acc[nt], 0, 0, 0);
        }
    }

    float* Og = O + ((size_t)b * SEQ + q0) * DIM;
    #pragma unroll
    for (int nt = 0; nt < 4; nt++)
        #pragma unroll
        for (int r = 0; r < 4; r++) {
            const int row = mrow + quad * 4 + r;        // C/D: row = quad*4 + reg
            const int col = n0 + nt * 16 + lm;          //      col = lane&15
            Og[row * DIM + col] = acc[nt][r];
        }
}

extern "C" void kernel_launch(void* const* d_in, const int* in_sizes, int n_in,
                              void* d_out, int out_size, void* d_ws, size_t ws_size,
                              hipStream_t stream) {
    const float* qk_sf = (const float*)d_in[1];
    const float* Q = (const float*)d_in[2];
    const float* K = (const float*)d_in[3];
    const float* V = (const float*)d_in[4];
    float* O = (float*)d_out;

    unsigned short* P  = (unsigned short*)d_ws;                       // 512*8192*2B = 8 MB
    unsigned short* Tt = (unsigned short*)((char*)d_ws + (size_t)512 * 8192 * 2);

    vtk_partial<<<dim3(512), dim3(256), 0, stream>>>(K, V, P);
    reduce_t<<<dim3(128), dim3(256), 0, stream>>>(P, qk_sf, Tt);
    qt_mfma<<<dim3(BATCH * 64), dim3(256), 0, stream>>>(Q, Tt, O);
}